// Round 10
// baseline (1935.764 us; speedup 1.0000x reference)
//
#include <hip/hip_runtime.h>
#include <hip/hip_bf16.h>
#include <hip/hip_fp16.h>

#define NN 50000
#define EE 800000
#define FF 256
#define HH 256
#define CC 10
#define BB 128
#define VV 4
#define SS 16    // pooling strips per batch
#define NBLK 196 // ceil(NN/256)
#define NSLAB 16 // feature slabs (16 feats x 4 views = 64 B/node/slab)
#define BPS 12500 // blocks per slab (NN/4 nodes, 4 waves/block)

typedef _Float16 half8v __attribute__((ext_vector_type(8)));
typedef float f32x4 __attribute__((ext_vector_type(4)));
typedef unsigned int uint4v __attribute__((ext_vector_type(4)));

__device__ inline float2 h2f(unsigned int u) {
  __half2 h = *reinterpret_cast<__half2*>(&u);
  return __half22float2(h);
}
// fp8 (OCP e4m3 on gfx950) pack/unpack: 4 values per uint
__device__ inline void fp8x4_to_f32(unsigned int u, float* f) {
  auto lo = __builtin_amdgcn_cvt_pk_f32_fp8(u, false);
  auto hi = __builtin_amdgcn_cvt_pk_f32_fp8(u, true);
  f[0] = lo[0]; f[1] = lo[1]; f[2] = hi[0]; f[3] = hi[1];
}
__device__ inline unsigned int f32x4_to_fp8(float a, float b, float c, float d) {
  int u = __builtin_amdgcn_cvt_pk_fp8_f32(a, b, 0, false);
  u = __builtin_amdgcn_cvt_pk_fp8_f32(c, d, u, true);
  return (unsigned int)u;
}

// ---------------- degree count (by row) ----------------
__global__ __launch_bounds__(256) void k_deg(const int* __restrict__ row, int* __restrict__ deg) {
  int i = blockIdx.x * 256 + threadIdx.x;
  if (i < EE) atomicAdd(&deg[row[i]], 1);
}

// ---------------- parallel scan ----------------
__global__ __launch_bounds__(256) void k_scan1(const int* __restrict__ deg, int* __restrict__ bsum) {
  int i = blockIdx.x * 256 + threadIdx.x;
  int v = (i < NN) ? deg[i] : 0;
  for (int o = 32; o > 0; o >>= 1) v += __shfl_down(v, o, 64);
  __shared__ int ws[4];
  if ((threadIdx.x & 63) == 0) ws[threadIdx.x >> 6] = v;
  __syncthreads();
  if (threadIdx.x == 0) bsum[blockIdx.x] = ws[0] + ws[1] + ws[2] + ws[3];
}

__global__ __launch_bounds__(256) void k_scan2(const int* __restrict__ bsum, int* __restrict__ boff) {
  __shared__ int tmp[256];
  int tid = threadIdx.x;
  int v = (tid < NBLK) ? bsum[tid] : 0;
  tmp[tid] = v;
  __syncthreads();
  for (int o = 1; o < 256; o <<= 1) {
    int t = 0;
    if (tid >= o) t = tmp[tid - o];
    __syncthreads();
    if (tid >= o) tmp[tid] += t;
    __syncthreads();
  }
  if (tid < NBLK) boff[tid] = tmp[tid] - v;
}

__global__ __launch_bounds__(256) void k_scan3(const int* __restrict__ deg,
                                               const int* __restrict__ boff,
                                               int* __restrict__ rptr) {
  __shared__ int tmp[256];
  int tid = threadIdx.x;
  int i = blockIdx.x * 256 + tid;
  int v = (i < NN) ? deg[i] : 0;
  tmp[tid] = v;
  __syncthreads();
  for (int o = 1; o < 256; o <<= 1) {
    int t = 0;
    if (tid >= o) t = tmp[tid - o];
    __syncthreads();
    if (tid >= o) tmp[tid] += t;
    __syncthreads();
  }
  int incl = tmp[tid];
  if (i < NN) rptr[i] = boff[blockIdx.x] + incl - v;
  if (i == NN - 1) rptr[NN] = boff[blockIdx.x] + incl;
}

// ---------------- scatter edges into CSR ----------------
__global__ __launch_bounds__(256) void k_scatter(const int* __restrict__ row,
                                                 const int* __restrict__ col,
                                                 const int* __restrict__ rptr,
                                                 int* __restrict__ fill,
                                                 int* __restrict__ csort) {
  int i = blockIdx.x * 256 + threadIdx.x;
  if (i < EE) {
    int r = row[i];
    int p = rptr[r] + atomicAdd(&fill[r], 1);
    csort[p] = col[i];
  }
}

// ---------------- batch_ptr via binary search ----------------
__global__ __launch_bounds__(256) void k_bptr(const int* __restrict__ batch, int* __restrict__ bptr) {
  int b = threadIdx.x;
  if (b > BB) return;
  int lo = 0, hi = NN;
  while (lo < hi) { int mid = (lo + hi) >> 1; if (batch[mid] < b) lo = mid + 1; else hi = mid; }
  bptr[b] = lo;
}

// ---------------- pack 4 mask planes into float4 AoS ----------------
__global__ __launch_bounds__(256) void k_packm(const float* __restrict__ nmask, float4* __restrict__ m4) {
  int i = blockIdx.x * 256 + threadIdx.x;
  if (i < NN)
    m4[i] = make_float4(nmask[i], nmask[NN + i], nmask[2 * NN + i], nmask[3 * NN + i]);
}

// ---------------- pack W1 into MFMA B-fragment order (fp16) ----------------
__global__ __launch_bounds__(256) void k_wfrag(const float* __restrict__ W, _Float16* __restrict__ wf) {
  int id = blockIdx.x * 256 + threadIdx.x;
  if (id >= 8 * 16 * 64) return;
  int lane = id & 63;
  int t = (id >> 6) & 15;
  int ks = id >> 10;
  int n = t * 16 + (lane & 15);
  int k0 = ks * 32 + (lane >> 4) * 8;
  half8v v;
#pragma unroll
  for (int j = 0; j < 8; ++j) v[j] = (_Float16)W[(size_t)(k0 + j) * HH + n];
  reinterpret_cast<half8v*>(wf)[id] = v;
}

// ---------------- Y = (X .* DM) @ W1 -> fp16 via MFMA, no LDS ----------------
__global__ __launch_bounds__(256) void k_gemm(const float* __restrict__ X,
                                              const float* __restrict__ DM,
                                              const _Float16* __restrict__ wf,
                                              __half* __restrict__ Z) {
  int w = threadIdx.x >> 6, lane = threadIdx.x & 63;
  int arow = blockIdx.x * 64 + w * 16 + (lane & 15);
  bool valid = arow < NN;
  const half8v* wfv = reinterpret_cast<const half8v*>(wf);
  f32x4 acc[16];
#pragma unroll
  for (int t = 0; t < 16; ++t) acc[t] = (f32x4){0.f, 0.f, 0.f, 0.f};
  for (int ks = 0; ks < 8; ++ks) {
    int k0 = ks * 32 + (lane >> 4) * 8;
    half8v a;
    if (valid) {
      const float4* xp = reinterpret_cast<const float4*>(X + (size_t)arow * FF + k0);
      const float4* dp = reinterpret_cast<const float4*>(DM + (size_t)arow * FF + k0);
      float4 x0 = xp[0], x1 = xp[1], d0 = dp[0], d1 = dp[1];
      a[0] = (_Float16)(x0.x * d0.x); a[1] = (_Float16)(x0.y * d0.y);
      a[2] = (_Float16)(x0.z * d0.z); a[3] = (_Float16)(x0.w * d0.w);
      a[4] = (_Float16)(x1.x * d1.x); a[5] = (_Float16)(x1.y * d1.y);
      a[6] = (_Float16)(x1.z * d1.z); a[7] = (_Float16)(x1.w * d1.w);
    } else {
#pragma unroll
      for (int j = 0; j < 8; ++j) a[j] = (_Float16)0.f;
    }
#pragma unroll
    for (int t = 0; t < 16; ++t) {
      half8v b = wfv[(size_t)(ks * 16 + t) * 64 + lane];
      acc[t] = __builtin_amdgcn_mfma_f32_16x16x32_f16(a, b, acc[t], 0, 0, 0);
    }
  }
  int mrow = blockIdx.x * 64 + w * 16 + (lane >> 4) * 4;
  int ncol = lane & 15;
#pragma unroll
  for (int t = 0; t < 16; ++t) {
#pragma unroll
    for (int r = 0; r < 4; ++r) {
      int rr = mrow + r;
      if (rr < NN) Z[(size_t)rr * HH + t * 16 + ncol] = __float2half(acc[t][r]);
    }
  }
}

// ---------------- y fp16 -> slab-major fp8: y8s[((s*NN + n)*4 + q] ----------------
__global__ __launch_bounds__(256) void k_cvt8s(const __half* __restrict__ y,
                                               unsigned int* __restrict__ y8s) {
  int i = blockIdx.x * 256 + threadIdx.x;  // NN*64 total
  if (i >= NN * 64) return;
  int n = i >> 6;
  int sq = i & 63;
  int s = sq >> 2, q = sq & 3;
  const uint2* yp = reinterpret_cast<const uint2*>(y + (size_t)n * FF + s * 16 + q * 4);
  uint2 raw = *yp;
  float2 lo = h2f(raw.x), hi = h2f(raw.y);
  y8s[((size_t)s * NN + n) * 4 + q] = f32x4_to_fp8(lo.x, lo.y, hi.x, hi.y);
}

// xcd-aware slab/node-quad decode
__device__ inline void slab_decode(int b, int& slab, int& nb) {
  int xcd = b & 7;
  int j = b >> 3;
  int half = (j >= BPS) ? 1 : 0;
  slab = xcd + 8 * half;
  nb = j - half * BPS;
}

// ---------------- hop1: wave-per-node edge-parallel, mask, write slab-interleaved ----------------
__global__ __launch_bounds__(256) void k_prop1e(const unsigned int* __restrict__ y8s,
                                                uint4v* __restrict__ h8,
                                                const int* __restrict__ rptr,
                                                const int* __restrict__ csort,
                                                const float4* __restrict__ m4) {
  int slab, nb;
  slab_decode(blockIdx.x, slab, nb);
  int w = threadIdx.x >> 6, lane = threadIdx.x & 63;
  int g = lane >> 2, q = lane & 3;
  int node = nb * 4 + w;
  const unsigned int* ip = y8s + (size_t)slab * NN * 4;
  int s = rptr[node], e = rptr[node + 1];
  float acc[16];
#pragma unroll
  for (int k = 0; k < 16; ++k) acc[k] = 0.f;
  if (g == 0) {
    float f[4];
    fp8x4_to_f32(ip[(size_t)node * 4 + q], f);
    float4 m = m4[node];
#pragma unroll
    for (int k = 0; k < 4; ++k) {
      acc[k] = f[k] * m.x; acc[4 + k] = f[k] * m.y;
      acc[8 + k] = f[k] * m.z; acc[12 + k] = f[k] * m.w;
    }
  }
  for (int j = s + g; j < e; j += 16) {
    int c = __builtin_nontemporal_load(&csort[j]);
    float f[4];
    fp8x4_to_f32(ip[(size_t)c * 4 + q], f);
    float4 m = m4[c];
#pragma unroll
    for (int k = 0; k < 4; ++k) {
      acc[k] += f[k] * m.x; acc[4 + k] += f[k] * m.y;
      acc[8 + k] += f[k] * m.z; acc[12 + k] += f[k] * m.w;
    }
  }
#pragma unroll
  for (int k = 0; k < 16; ++k) {
    acc[k] += __shfl_xor(acc[k], 4, 64);
    acc[k] += __shfl_xor(acc[k], 8, 64);
    acc[k] += __shfl_xor(acc[k], 16, 64);
    acc[k] += __shfl_xor(acc[k], 32, 64);
  }
  if (g == 0) {
    float sc = 1.0f / (float)(e - s + 1);
    uint4v o;
    o.x = f32x4_to_fp8(acc[0] * sc, acc[1] * sc, acc[2] * sc, acc[3] * sc);
    o.y = f32x4_to_fp8(acc[4] * sc, acc[5] * sc, acc[6] * sc, acc[7] * sc);
    o.z = f32x4_to_fp8(acc[8] * sc, acc[9] * sc, acc[10] * sc, acc[11] * sc);
    o.w = f32x4_to_fp8(acc[12] * sc, acc[13] * sc, acc[14] * sc, acc[15] * sc);
    __builtin_nontemporal_store(o, &h8[((size_t)slab * NN + node) * 4 + q]);
  }
}

// ---------------- hop2: wave-per-node edge-parallel slab gather -> slab (NT) ----------------
__global__ __launch_bounds__(256) void k_prop2e(const uint4v* __restrict__ in,
                                                uint4v* __restrict__ out,
                                                const int* __restrict__ rptr,
                                                const int* __restrict__ csort) {
  int slab, nb;
  slab_decode(blockIdx.x, slab, nb);
  int w = threadIdx.x >> 6, lane = threadIdx.x & 63;
  int g = lane >> 2, q = lane & 3;
  int node = nb * 4 + w;
  const uint4v* ip = in + (size_t)slab * NN * 4;
  int s = rptr[node], e = rptr[node + 1];
  float acc[16];
#pragma unroll
  for (int k = 0; k < 16; ++k) acc[k] = 0.f;
  if (g == 0) {
    uint4v r = ip[(size_t)node * 4 + q];
    fp8x4_to_f32(r.x, acc); fp8x4_to_f32(r.y, acc + 4);
    fp8x4_to_f32(r.z, acc + 8); fp8x4_to_f32(r.w, acc + 12);
  }
  for (int j = s + g; j < e; j += 16) {
    int c = __builtin_nontemporal_load(&csort[j]);
    uint4v r = ip[(size_t)c * 4 + q];
    float f[16];
    fp8x4_to_f32(r.x, f); fp8x4_to_f32(r.y, f + 4);
    fp8x4_to_f32(r.z, f + 8); fp8x4_to_f32(r.w, f + 12);
#pragma unroll
    for (int k = 0; k < 16; ++k) acc[k] += f[k];
  }
#pragma unroll
  for (int k = 0; k < 16; ++k) {
    acc[k] += __shfl_xor(acc[k], 4, 64);
    acc[k] += __shfl_xor(acc[k], 8, 64);
    acc[k] += __shfl_xor(acc[k], 16, 64);
    acc[k] += __shfl_xor(acc[k], 32, 64);
  }
  if (g == 0) {
    float sc = 1.0f / (float)(e - s + 1);
    uint4v o;
    o.x = f32x4_to_fp8(acc[0] * sc, acc[1] * sc, acc[2] * sc, acc[3] * sc);
    o.y = f32x4_to_fp8(acc[4] * sc, acc[5] * sc, acc[6] * sc, acc[7] * sc);
    o.z = f32x4_to_fp8(acc[8] * sc, acc[9] * sc, acc[10] * sc, acc[11] * sc);
    o.w = f32x4_to_fp8(acc[12] * sc, acc[13] * sc, acc[14] * sc, acc[15] * sc);
    __builtin_nontemporal_store(o, &out[((size_t)slab * NN + node) * 4 + q]);
  }
}

// ---------------- hop3: wave-per-node edge-parallel + bias + relu + pool ----------------
__global__ __launch_bounds__(256) void k_prop3e(const uint4v* __restrict__ in,
                                                const int* __restrict__ rptr,
                                                const int* __restrict__ csort,
                                                const int* __restrict__ batch,
                                                const float* __restrict__ b1,
                                                float* __restrict__ part) {
  int slab, nb;
  slab_decode(blockIdx.x, slab, nb);
  int tid = threadIdx.x;
  int w = tid >> 6, lane = tid & 63;
  int g = lane >> 2, q = lane & 3;
  int node = nb * 4 + w;
  __shared__ float red[4][64];
  __shared__ int blkuni, b0s;
  const uint4v* ip = in + (size_t)slab * NN * 4;
  int s = rptr[node], e = rptr[node + 1];
  float acc[16];
#pragma unroll
  for (int k = 0; k < 16; ++k) acc[k] = 0.f;
  if (g == 0) {
    uint4v r = ip[(size_t)node * 4 + q];
    fp8x4_to_f32(r.x, acc); fp8x4_to_f32(r.y, acc + 4);
    fp8x4_to_f32(r.z, acc + 8); fp8x4_to_f32(r.w, acc + 12);
  }
  for (int j = s + g; j < e; j += 16) {
    int c = __builtin_nontemporal_load(&csort[j]);
    uint4v r = ip[(size_t)c * 4 + q];
    float f[16];
    fp8x4_to_f32(r.x, f); fp8x4_to_f32(r.y, f + 4);
    fp8x4_to_f32(r.z, f + 8); fp8x4_to_f32(r.w, f + 12);
#pragma unroll
    for (int k = 0; k < 16; ++k) acc[k] += f[k];
  }
#pragma unroll
  for (int k = 0; k < 16; ++k) {
    acc[k] += __shfl_xor(acc[k], 4, 64);
    acc[k] += __shfl_xor(acc[k], 8, 64);
    acc[k] += __shfl_xor(acc[k], 16, 64);
    acc[k] += __shfl_xor(acc[k], 32, 64);
  }
  float r16[16];
  if (g == 0) {
    float sc = 1.0f / (float)(e - s + 1);
    float4 bv = *reinterpret_cast<const float4*>(&b1[slab * 16 + q * 4]);
    float bk[4] = {bv.x, bv.y, bv.z, bv.w};
#pragma unroll
    for (int v = 0; v < 4; ++v)
#pragma unroll
      for (int k = 0; k < 4; ++k)
        r16[v * 4 + k] = fmaxf(acc[v * 4 + k] * sc + bk[k], 0.f);
#pragma unroll
    for (int k = 0; k < 16; ++k) red[w][q * 16 + k] = r16[k];
  }
  if (tid == 0) {
    b0s = batch[nb * 4];
    blkuni = (batch[nb * 4] == batch[nb * 4 + 3]) ? 1 : 0;
  }
  __syncthreads();
  int strip = nb & (SS - 1);
  if (blkuni) {
    if (tid < 64) {
      float sum = red[0][tid] + red[1][tid] + red[2][tid] + red[3][tid];
      int qq = tid >> 4, idx = tid & 15;
      int view = idx >> 2, k = idx & 3;
      int feat = slab * 16 + qq * 4 + k;
      atomicAdd(&part[(((size_t)view * SS + strip) * BB + b0s) * HH + feat], sum);
    }
  } else if (g == 0) {
    int bn = batch[node];
#pragma unroll
    for (int k = 0; k < 16; ++k) {
      int view = k >> 2, kk = k & 3;
      int feat = slab * 16 + q * 4 + kk;
      atomicAdd(&part[(((size_t)view * SS + strip) * BB + bn) * HH + feat], r16[k]);
    }
  }
}

// ---------------- head: meanpool -> @W2+b2 -> @Wc+bc -> softmax ----------------
__global__ __launch_bounds__(256) void k_head(const float* __restrict__ part,
                                              const int* __restrict__ bptr,
                                              const float* __restrict__ W2,
                                              const float* __restrict__ b2,
                                              const float* __restrict__ Wc,
                                              const float* __restrict__ bc,
                                              float* __restrict__ probs,
                                              float* __restrict__ logits) {
  int v = blockIdx.x / BB;
  int b = blockIdx.x % BB;
  int h = threadIdx.x;
  __shared__ float mr[HH];
  __shared__ float vr[HH];
  __shared__ float scs[CC];
  float acc = 0.f;
  for (int s = 0; s < SS; ++s)
    acc += part[(((size_t)v * SS + s) * BB + b) * HH + h];
  int cnt = bptr[b + 1] - bptr[b]; if (cnt < 1) cnt = 1;
  mr[h] = acc / (float)cnt;
  __syncthreads();
  float a = b2[h];
  for (int k = 0; k < HH; ++k) a += mr[k] * W2[k * HH + h];
  vr[h] = a;
  __syncthreads();
  if (h < CC) {
    float t = bc[h];
    for (int k = 0; k < HH; ++k) t += vr[k] * Wc[k * CC + h];
    scs[h] = t;
  }
  __syncthreads();
  if (h < CC) {
    float m = scs[0];
    for (int c = 1; c < CC; ++c) m = fmaxf(m, scs[c]);
    float den = 0.f;
    for (int c = 0; c < CC; ++c) den += expf(scs[c] - m);
    float p = expf(scs[h] - m) / den;
    probs[((size_t)v * BB + b) * CC + h] = p;
    if (v == 0) logits[b * CC + h] = scs[h];
  }
}

// ---------------- loss: consistency + entropy ----------------
__global__ __launch_bounds__(256) void k_loss(const float* __restrict__ probs, float* __restrict__ out) {
  __shared__ float mp[BB * CC];
  __shared__ float red[8];
  int tid = threadIdx.x;
  float ent = 0.f;
  for (int i = tid; i < BB * CC; i += 256) {
    float m = 0.25f * (probs[i] + probs[BB * CC + i] + probs[2 * BB * CC + i] + probs[3 * BB * CC + i]);
    mp[i] = m;
    ent += m * logf(m + 1e-8f);
  }
  __syncthreads();
  float cons = 0.f;
  for (int i = tid; i < VV * BB * CC; i += 256) {
    float d = probs[i] - mp[i % (BB * CC)];
    cons += d * d;
  }
  for (int o = 32; o > 0; o >>= 1) {
    cons += __shfl_down(cons, o, 64);
    ent += __shfl_down(ent, o, 64);
  }
  int wid = tid >> 6, lane = tid & 63;
  if (lane == 0) { red[wid] = cons; red[4 + wid] = ent; }
  __syncthreads();
  if (tid == 0) {
    float c = red[0] + red[1] + red[2] + red[3];
    float e2 = red[4] + red[5] + red[6] + red[7];
    out[0] = c / (float)(VV * BB) - e2 / (float)BB;
  }
}

extern "C" void kernel_launch(void* const* d_in, const int* in_sizes, int n_in,
                              void* d_out, int out_size, void* d_ws, size_t ws_size,
                              hipStream_t stream) {
  const float* x     = (const float*)d_in[0];
  const int*   erow  = (const int*)d_in[1];
  const int*   ecol  = ((const int*)d_in[1]) + EE;
  const int*   batch = (const int*)d_in[2];
  const float* dm    = (const float*)d_in[3];
  const float* nmask = (const float*)d_in[4];
  const float* W1    = (const float*)d_in[5];
  const float* b1    = (const float*)d_in[6];
  const float* W2    = (const float*)d_in[7];
  const float* b2    = (const float*)d_in[8];
  const float* Wc    = (const float*)d_in[9];
  const float* bc    = (const float*)d_in[10];
  float* out = (float*)d_out;

  char* ws = (char*)d_ws;
  size_t off = 0;
  auto carve = [&](size_t bytes) -> char* {
    char* p = ws + off;
    off = (off + bytes + 255) & ~(size_t)255;
    return p;
  };
  float* part  = (float*)carve((size_t)VV * SS * BB * HH * 4);
  int*   deg   = (int*)carve((size_t)NN * 4);
  int*   fill  = (int*)carve((size_t)NN * 4);
  int*   rptr  = (int*)carve((size_t)(NN + 1) * 4);
  int*   csort = (int*)carve((size_t)EE * 4);
  int*   bptr  = (int*)carve((size_t)(BB + 1) * 4);
  int*   bsum  = (int*)carve(256 * 4);
  int*   boff  = (int*)carve(256 * 4);
  float* probs = (float*)carve((size_t)VV * BB * CC * 4);
  float4* m4   = (float4*)carve((size_t)NN * 16);
  _Float16* wf = (_Float16*)carve((size_t)8 * 16 * 64 * 8 * 2);

  const size_t NFh = (size_t)NN * FF * 2;
  __half* y  = (__half*)carve(NFh);                                // GEMM out fp16
  unsigned int* y8s = (unsigned int*)carve((size_t)NN * 256);      // 12.8 MB slab-major fp8
  uint4v* h8a = (uint4v*)carve((size_t)NSLAB * NN * 64);           // 51.2 MB slab-interleaved
  uint4v* h8b = (uint4v*)carve((size_t)NSLAB * NN * 64);           // 51.2 MB

  hipMemsetAsync(deg, 0, (size_t)NN * 4, stream);
  hipMemsetAsync(fill, 0, (size_t)NN * 4, stream);
  hipMemsetAsync(part, 0, (size_t)VV * SS * BB * HH * 4, stream);

  k_deg<<<(EE + 255) / 256, 256, 0, stream>>>(erow, deg);
  k_scan1<<<NBLK, 256, 0, stream>>>(deg, bsum);
  k_scan2<<<1, 256, 0, stream>>>(bsum, boff);
  k_scan3<<<NBLK, 256, 0, stream>>>(deg, boff, rptr);
  k_scatter<<<(EE + 255) / 256, 256, 0, stream>>>(erow, ecol, rptr, fill, csort);
  k_bptr<<<1, 256, 0, stream>>>(batch, bptr);
  k_packm<<<(NN + 255) / 256, 256, 0, stream>>>(nmask, m4);
  k_wfrag<<<32, 256, 0, stream>>>(W1, wf);

  k_gemm<<<(NN + 63) / 64, 256, 0, stream>>>(x, dm, wf, y);
  k_cvt8s<<<(NN * 64 + 255) / 256, 256, 0, stream>>>(y, y8s);
  k_prop1e<<<NSLAB * BPS, 256, 0, stream>>>(y8s, h8a, rptr, csort, m4);
  k_prop2e<<<NSLAB * BPS, 256, 0, stream>>>(h8a, h8b, rptr, csort);
  k_prop3e<<<NSLAB * BPS, 256, 0, stream>>>(h8b, rptr, csort, batch, b1, part);
  k_head<<<VV * BB, 256, 0, stream>>>(part, bptr, W2, b2, Wc, bc, probs, out);
  k_loss<<<1, 256, 0, stream>>>(probs, out + BB * CC);
}

// Round 11
// 624.989 us; speedup vs baseline: 3.0973x; 3.0973x over previous
//
#include <hip/hip_runtime.h>
#include <hip/hip_bf16.h>
#include <hip/hip_fp16.h>

#define NN 50000
#define EE 800000
#define FF 256
#define HH 256
#define CC 10
#define BB 128
#define VV 4
#define SS 16    // pooling strips per batch
#define NBLK 196 // ceil(NN/256)
#define BPV 12500 // node-quads (NN/4)

typedef _Float16 half8v __attribute__((ext_vector_type(8)));
typedef float f32x4 __attribute__((ext_vector_type(4)));

// fp16 pack/unpack helpers
__device__ inline float2 h2f(unsigned int u) {
  __half2 h = *reinterpret_cast<__half2*>(&u);
  return __half22float2(h);
}
// fp8 (OCP e4m3 on gfx950) pack/unpack: 4 values per uint
__device__ inline void fp8x4_to_f32(unsigned int u, float* f) {
  auto lo = __builtin_amdgcn_cvt_pk_f32_fp8(u, false);
  auto hi = __builtin_amdgcn_cvt_pk_f32_fp8(u, true);
  f[0] = lo[0]; f[1] = lo[1]; f[2] = hi[0]; f[3] = hi[1];
}
__device__ inline unsigned int f32x4_to_fp8(float a, float b, float c, float d) {
  int u = __builtin_amdgcn_cvt_pk_fp8_f32(a, b, 0, false);
  u = __builtin_amdgcn_cvt_pk_fp8_f32(c, d, u, true);
  return (unsigned int)u;
}

// ---------------- degree count (by row) ----------------
__global__ __launch_bounds__(256) void k_deg(const int* __restrict__ row, int* __restrict__ deg) {
  int i = blockIdx.x * 256 + threadIdx.x;
  if (i < EE) atomicAdd(&deg[row[i]], 1);
}

// ---------------- parallel scan ----------------
__global__ __launch_bounds__(256) void k_scan1(const int* __restrict__ deg, int* __restrict__ bsum) {
  int i = blockIdx.x * 256 + threadIdx.x;
  int v = (i < NN) ? deg[i] : 0;
  for (int o = 32; o > 0; o >>= 1) v += __shfl_down(v, o, 64);
  __shared__ int ws[4];
  if ((threadIdx.x & 63) == 0) ws[threadIdx.x >> 6] = v;
  __syncthreads();
  if (threadIdx.x == 0) bsum[blockIdx.x] = ws[0] + ws[1] + ws[2] + ws[3];
}

__global__ __launch_bounds__(256) void k_scan2(const int* __restrict__ bsum, int* __restrict__ boff) {
  __shared__ int tmp[256];
  int tid = threadIdx.x;
  int v = (tid < NBLK) ? bsum[tid] : 0;
  tmp[tid] = v;
  __syncthreads();
  for (int o = 1; o < 256; o <<= 1) {
    int t = 0;
    if (tid >= o) t = tmp[tid - o];
    __syncthreads();
    if (tid >= o) tmp[tid] += t;
    __syncthreads();
  }
  if (tid < NBLK) boff[tid] = tmp[tid] - v;
}

__global__ __launch_bounds__(256) void k_scan3(const int* __restrict__ deg,
                                               const int* __restrict__ boff,
                                               int* __restrict__ rptr) {
  __shared__ int tmp[256];
  int tid = threadIdx.x;
  int i = blockIdx.x * 256 + tid;
  int v = (i < NN) ? deg[i] : 0;
  tmp[tid] = v;
  __syncthreads();
  for (int o = 1; o < 256; o <<= 1) {
    int t = 0;
    if (tid >= o) t = tmp[tid - o];
    __syncthreads();
    if (tid >= o) tmp[tid] += t;
    __syncthreads();
  }
  int incl = tmp[tid];
  if (i < NN) rptr[i] = boff[blockIdx.x] + incl - v;
  if (i == NN - 1) rptr[NN] = boff[blockIdx.x] + incl;
}

// ---------------- scatter edges into CSR ----------------
__global__ __launch_bounds__(256) void k_scatter(const int* __restrict__ row,
                                                 const int* __restrict__ col,
                                                 const int* __restrict__ rptr,
                                                 int* __restrict__ fill,
                                                 int* __restrict__ csort) {
  int i = blockIdx.x * 256 + threadIdx.x;
  if (i < EE) {
    int r = row[i];
    int p = rptr[r] + atomicAdd(&fill[r], 1);
    csort[p] = col[i];
  }
}

// ---------------- batch_ptr via binary search ----------------
__global__ __launch_bounds__(256) void k_bptr(const int* __restrict__ batch, int* __restrict__ bptr) {
  int b = threadIdx.x;
  if (b > BB) return;
  int lo = 0, hi = NN;
  while (lo < hi) { int mid = (lo + hi) >> 1; if (batch[mid] < b) lo = mid + 1; else hi = mid; }
  bptr[b] = lo;
}

// ---------------- pack 4 mask planes into float4 AoS ----------------
__global__ __launch_bounds__(256) void k_packm(const float* __restrict__ nmask, float4* __restrict__ m4) {
  int i = blockIdx.x * 256 + threadIdx.x;
  if (i < NN)
    m4[i] = make_float4(nmask[i], nmask[NN + i], nmask[2 * NN + i], nmask[3 * NN + i]);
}

// ---------------- pack W1 into MFMA B-fragment order (fp16) ----------------
__global__ __launch_bounds__(256) void k_wfrag(const float* __restrict__ W, _Float16* __restrict__ wf) {
  int id = blockIdx.x * 256 + threadIdx.x;
  if (id >= 8 * 16 * 64) return;
  int lane = id & 63;
  int t = (id >> 6) & 15;
  int ks = id >> 10;
  int n = t * 16 + (lane & 15);
  int k0 = ks * 32 + (lane >> 4) * 8;
  half8v v;
#pragma unroll
  for (int j = 0; j < 8; ++j) v[j] = (_Float16)W[(size_t)(k0 + j) * HH + n];
  reinterpret_cast<half8v*>(wf)[id] = v;
}

// ---------------- Y = (X .* DM) @ W1 -> fp16 via MFMA, no LDS ----------------
__global__ __launch_bounds__(256) void k_gemm(const float* __restrict__ X,
                                              const float* __restrict__ DM,
                                              const _Float16* __restrict__ wf,
                                              __half* __restrict__ Z) {
  int w = threadIdx.x >> 6, lane = threadIdx.x & 63;
  int arow = blockIdx.x * 64 + w * 16 + (lane & 15);
  bool valid = arow < NN;
  const half8v* wfv = reinterpret_cast<const half8v*>(wf);
  f32x4 acc[16];
#pragma unroll
  for (int t = 0; t < 16; ++t) acc[t] = (f32x4){0.f, 0.f, 0.f, 0.f};
  for (int ks = 0; ks < 8; ++ks) {
    int k0 = ks * 32 + (lane >> 4) * 8;
    half8v a;
    if (valid) {
      const float4* xp = reinterpret_cast<const float4*>(X + (size_t)arow * FF + k0);
      const float4* dp = reinterpret_cast<const float4*>(DM + (size_t)arow * FF + k0);
      float4 x0 = xp[0], x1 = xp[1], d0 = dp[0], d1 = dp[1];
      a[0] = (_Float16)(x0.x * d0.x); a[1] = (_Float16)(x0.y * d0.y);
      a[2] = (_Float16)(x0.z * d0.z); a[3] = (_Float16)(x0.w * d0.w);
      a[4] = (_Float16)(x1.x * d1.x); a[5] = (_Float16)(x1.y * d1.y);
      a[6] = (_Float16)(x1.z * d1.z); a[7] = (_Float16)(x1.w * d1.w);
    } else {
#pragma unroll
      for (int j = 0; j < 8; ++j) a[j] = (_Float16)0.f;
    }
#pragma unroll
    for (int t = 0; t < 16; ++t) {
      half8v b = wfv[(size_t)(ks * 16 + t) * 64 + lane];
      acc[t] = __builtin_amdgcn_mfma_f32_16x16x32_f16(a, b, acc[t], 0, 0, 0);
    }
  }
  int mrow = blockIdx.x * 64 + w * 16 + (lane >> 4) * 4;
  int ncol = lane & 15;
#pragma unroll
  for (int t = 0; t < 16; ++t) {
#pragma unroll
    for (int r = 0; r < 4; ++r) {
      int rr = mrow + r;
      if (rr < NN) Z[(size_t)rr * HH + t * 16 + ncol] = __float2half(acc[t][r]);
    }
  }
}

// ---------------- hop1 merged over views: fp16 y gather (8 B/lane), interleaved uint4 fp8 out ----
__global__ __launch_bounds__(256) void k_prop1(const __half* __restrict__ y,
                                               uint4* __restrict__ h8,
                                               const int* __restrict__ rptr,
                                               const int* __restrict__ csort,
                                               const float4* __restrict__ m4) {
  int node = blockIdx.x * 4 + (threadIdx.x >> 6);
  int lane = threadIdx.x & 63;
  const uint2* in2 = reinterpret_cast<const uint2*>(y);
  int s = rptr[node], e = rptr[node + 1];
  float4 a0, a1, a2, a3;
  {
    uint2 raw = in2[(size_t)node * 64 + lane];
    float2 lo = h2f(raw.x), hi = h2f(raw.y);
    float4 m = m4[node];
    a0 = make_float4(lo.x * m.x, lo.y * m.x, hi.x * m.x, hi.y * m.x);
    a1 = make_float4(lo.x * m.y, lo.y * m.y, hi.x * m.y, hi.y * m.y);
    a2 = make_float4(lo.x * m.z, lo.y * m.z, hi.x * m.z, hi.y * m.z);
    a3 = make_float4(lo.x * m.w, lo.y * m.w, hi.x * m.w, hi.y * m.w);
  }
  int j = s;
  for (; j + 1 < e; j += 2) {
    int c0 = csort[j], c1 = csort[j + 1];
    uint2 r0 = in2[(size_t)c0 * 64 + lane];
    uint2 r1 = in2[(size_t)c1 * 64 + lane];
    float2 l0 = h2f(r0.x), u0 = h2f(r0.y);
    float2 l1 = h2f(r1.x), u1 = h2f(r1.y);
    float4 p = m4[c0];
    float4 q = m4[c1];
    a0.x += l0.x * p.x + l1.x * q.x; a0.y += l0.y * p.x + l1.y * q.x;
    a0.z += u0.x * p.x + u1.x * q.x; a0.w += u0.y * p.x + u1.y * q.x;
    a1.x += l0.x * p.y + l1.x * q.y; a1.y += l0.y * p.y + l1.y * q.y;
    a1.z += u0.x * p.y + u1.x * q.y; a1.w += u0.y * p.y + u1.y * q.y;
    a2.x += l0.x * p.z + l1.x * q.z; a2.y += l0.y * p.z + l1.y * q.z;
    a2.z += u0.x * p.z + u1.x * q.z; a2.w += u0.y * p.z + u1.y * q.z;
    a3.x += l0.x * p.w + l1.x * q.w; a3.y += l0.y * p.w + l1.y * q.w;
    a3.z += u0.x * p.w + u1.x * q.w; a3.w += u0.y * p.w + u1.y * q.w;
  }
  if (j < e) {
    int c0 = csort[j];
    uint2 r0 = in2[(size_t)c0 * 64 + lane];
    float2 l0 = h2f(r0.x), u0 = h2f(r0.y);
    float4 p = m4[c0];
    a0.x += l0.x * p.x; a0.y += l0.y * p.x; a0.z += u0.x * p.x; a0.w += u0.y * p.x;
    a1.x += l0.x * p.y; a1.y += l0.y * p.y; a1.z += u0.x * p.y; a1.w += u0.y * p.y;
    a2.x += l0.x * p.z; a2.y += l0.y * p.z; a2.z += u0.x * p.z; a2.w += u0.y * p.z;
    a3.x += l0.x * p.w; a3.y += l0.y * p.w; a3.z += u0.x * p.w; a3.w += u0.y * p.w;
  }
  float sc = 1.0f / (float)(e - s + 1);
  uint4 o;
  o.x = f32x4_to_fp8(a0.x * sc, a0.y * sc, a0.z * sc, a0.w * sc);
  o.y = f32x4_to_fp8(a1.x * sc, a1.y * sc, a1.z * sc, a1.w * sc);
  o.z = f32x4_to_fp8(a2.x * sc, a2.y * sc, a2.z * sc, a2.w * sc);
  o.w = f32x4_to_fp8(a3.x * sc, a3.y * sc, a3.z * sc, a3.w * sc);
  h8[(size_t)node * 64 + lane] = o;
}

// ---------------- hop2 all views: uint4 gather -> uint4 write (round-7 measured 123 us) -------
__global__ __launch_bounds__(256) void k_prop2a(const uint4* __restrict__ in,
                                                uint4* __restrict__ out,
                                                const int* __restrict__ rptr,
                                                const int* __restrict__ csort) {
  int node = blockIdx.x * 4 + (threadIdx.x >> 6);
  int lane = threadIdx.x & 63;
  int s = rptr[node], e = rptr[node + 1];
  float4 a0, a1, a2, a3;
  {
    uint4 r = in[(size_t)node * 64 + lane];
    float f0[4], f1[4], f2[4], f3[4];
    fp8x4_to_f32(r.x, f0); fp8x4_to_f32(r.y, f1);
    fp8x4_to_f32(r.z, f2); fp8x4_to_f32(r.w, f3);
    a0 = make_float4(f0[0], f0[1], f0[2], f0[3]);
    a1 = make_float4(f1[0], f1[1], f1[2], f1[3]);
    a2 = make_float4(f2[0], f2[1], f2[2], f2[3]);
    a3 = make_float4(f3[0], f3[1], f3[2], f3[3]);
  }
  int j = s;
  for (; j + 1 < e; j += 2) {
    int c0 = csort[j], c1 = csort[j + 1];
    uint4 r0 = in[(size_t)c0 * 64 + lane];
    uint4 r1 = in[(size_t)c1 * 64 + lane];
    float g0[4], g1[4], g2[4], g3[4], h0[4], h1v[4], h2v[4], h3[4];
    fp8x4_to_f32(r0.x, g0); fp8x4_to_f32(r0.y, g1);
    fp8x4_to_f32(r0.z, g2); fp8x4_to_f32(r0.w, g3);
    fp8x4_to_f32(r1.x, h0); fp8x4_to_f32(r1.y, h1v);
    fp8x4_to_f32(r1.z, h2v); fp8x4_to_f32(r1.w, h3);
    a0.x += g0[0] + h0[0]; a0.y += g0[1] + h0[1]; a0.z += g0[2] + h0[2]; a0.w += g0[3] + h0[3];
    a1.x += g1[0] + h1v[0]; a1.y += g1[1] + h1v[1]; a1.z += g1[2] + h1v[2]; a1.w += g1[3] + h1v[3];
    a2.x += g2[0] + h2v[0]; a2.y += g2[1] + h2v[1]; a2.z += g2[2] + h2v[2]; a2.w += g2[3] + h2v[3];
    a3.x += g3[0] + h3[0]; a3.y += g3[1] + h3[1]; a3.z += g3[2] + h3[2]; a3.w += g3[3] + h3[3];
  }
  if (j < e) {
    int c0 = csort[j];
    uint4 r0 = in[(size_t)c0 * 64 + lane];
    float g0[4], g1[4], g2[4], g3[4];
    fp8x4_to_f32(r0.x, g0); fp8x4_to_f32(r0.y, g1);
    fp8x4_to_f32(r0.z, g2); fp8x4_to_f32(r0.w, g3);
    a0.x += g0[0]; a0.y += g0[1]; a0.z += g0[2]; a0.w += g0[3];
    a1.x += g1[0]; a1.y += g1[1]; a1.z += g1[2]; a1.w += g1[3];
    a2.x += g2[0]; a2.y += g2[1]; a2.z += g2[2]; a2.w += g2[3];
    a3.x += g3[0]; a3.y += g3[1]; a3.z += g3[2]; a3.w += g3[3];
  }
  float sc = 1.0f / (float)(e - s + 1);
  uint4 o;
  o.x = f32x4_to_fp8(a0.x * sc, a0.y * sc, a0.z * sc, a0.w * sc);
  o.y = f32x4_to_fp8(a1.x * sc, a1.y * sc, a1.z * sc, a1.w * sc);
  o.z = f32x4_to_fp8(a2.x * sc, a2.y * sc, a2.z * sc, a2.w * sc);
  o.w = f32x4_to_fp8(a3.x * sc, a3.y * sc, a3.z * sc, a3.w * sc);
  out[(size_t)node * 64 + lane] = o;
}

// ---------------- hop3 all views + bias + relu + pool (round-7 measured 123 us) --------------
__global__ __launch_bounds__(256) void k_prop3a(const uint4* __restrict__ in,
                                                const int* __restrict__ rptr,
                                                const int* __restrict__ csort,
                                                const int* __restrict__ batch,
                                                const float* __restrict__ b1,
                                                float* __restrict__ part) {
  int w = threadIdx.x >> 6, lane = threadIdx.x & 63;
  int node = blockIdx.x * 4 + w;
  __shared__ float red[4][VV][HH];  // 16 KB
  __shared__ int bb[4];
  int s = rptr[node], e = rptr[node + 1];
  float4 a0, a1, a2, a3;
  {
    uint4 r = in[(size_t)node * 64 + lane];
    float f0[4], f1[4], f2[4], f3[4];
    fp8x4_to_f32(r.x, f0); fp8x4_to_f32(r.y, f1);
    fp8x4_to_f32(r.z, f2); fp8x4_to_f32(r.w, f3);
    a0 = make_float4(f0[0], f0[1], f0[2], f0[3]);
    a1 = make_float4(f1[0], f1[1], f1[2], f1[3]);
    a2 = make_float4(f2[0], f2[1], f2[2], f2[3]);
    a3 = make_float4(f3[0], f3[1], f3[2], f3[3]);
  }
  int j = s;
  for (; j + 1 < e; j += 2) {
    int c0 = csort[j], c1 = csort[j + 1];
    uint4 r0 = in[(size_t)c0 * 64 + lane];
    uint4 r1 = in[(size_t)c1 * 64 + lane];
    float g0[4], g1[4], g2[4], g3[4], h0[4], h1v[4], h2v[4], h3[4];
    fp8x4_to_f32(r0.x, g0); fp8x4_to_f32(r0.y, g1);
    fp8x4_to_f32(r0.z, g2); fp8x4_to_f32(r0.w, g3);
    fp8x4_to_f32(r1.x, h0); fp8x4_to_f32(r1.y, h1v);
    fp8x4_to_f32(r1.z, h2v); fp8x4_to_f32(r1.w, h3);
    a0.x += g0[0] + h0[0]; a0.y += g0[1] + h0[1]; a0.z += g0[2] + h0[2]; a0.w += g0[3] + h0[3];
    a1.x += g1[0] + h1v[0]; a1.y += g1[1] + h1v[1]; a1.z += g1[2] + h1v[2]; a1.w += g1[3] + h1v[3];
    a2.x += g2[0] + h2v[0]; a2.y += g2[1] + h2v[1]; a2.z += g2[2] + h2v[2]; a2.w += g2[3] + h2v[3];
    a3.x += g3[0] + h3[0]; a3.y += g3[1] + h3[1]; a3.z += g3[2] + h3[2]; a3.w += g3[3] + h3[3];
  }
  if (j < e) {
    int c0 = csort[j];
    uint4 r0 = in[(size_t)c0 * 64 + lane];
    float g0[4], g1[4], g2[4], g3[4];
    fp8x4_to_f32(r0.x, g0); fp8x4_to_f32(r0.y, g1);
    fp8x4_to_f32(r0.z, g2); fp8x4_to_f32(r0.w, g3);
    a0.x += g0[0]; a0.y += g0[1]; a0.z += g0[2]; a0.w += g0[3];
    a1.x += g1[0]; a1.y += g1[1]; a1.z += g1[2]; a1.w += g1[3];
    a2.x += g2[0]; a2.y += g2[1]; a2.z += g2[2]; a2.w += g2[3];
    a3.x += g3[0]; a3.y += g3[1]; a3.z += g3[2]; a3.w += g3[3];
  }
  float sc = 1.0f / (float)(e - s + 1);
  float4 bv = *reinterpret_cast<const float4*>(&b1[lane * 4]);
  red[w][0][lane * 4 + 0] = fmaxf(a0.x * sc + bv.x, 0.f);
  red[w][0][lane * 4 + 1] = fmaxf(a0.y * sc + bv.y, 0.f);
  red[w][0][lane * 4 + 2] = fmaxf(a0.z * sc + bv.z, 0.f);
  red[w][0][lane * 4 + 3] = fmaxf(a0.w * sc + bv.w, 0.f);
  red[w][1][lane * 4 + 0] = fmaxf(a1.x * sc + bv.x, 0.f);
  red[w][1][lane * 4 + 1] = fmaxf(a1.y * sc + bv.y, 0.f);
  red[w][1][lane * 4 + 2] = fmaxf(a1.z * sc + bv.z, 0.f);
  red[w][1][lane * 4 + 3] = fmaxf(a1.w * sc + bv.w, 0.f);
  red[w][2][lane * 4 + 0] = fmaxf(a2.x * sc + bv.x, 0.f);
  red[w][2][lane * 4 + 1] = fmaxf(a2.y * sc + bv.y, 0.f);
  red[w][2][lane * 4 + 2] = fmaxf(a2.z * sc + bv.z, 0.f);
  red[w][2][lane * 4 + 3] = fmaxf(a2.w * sc + bv.w, 0.f);
  red[w][3][lane * 4 + 0] = fmaxf(a3.x * sc + bv.x, 0.f);
  red[w][3][lane * 4 + 1] = fmaxf(a3.y * sc + bv.y, 0.f);
  red[w][3][lane * 4 + 2] = fmaxf(a3.z * sc + bv.z, 0.f);
  red[w][3][lane * 4 + 3] = fmaxf(a3.w * sc + bv.w, 0.f);
  if (lane == 0) bb[w] = batch[node];
  __syncthreads();
  int strip = blockIdx.x & (SS - 1);
  if (bb[0] == bb[1] && bb[1] == bb[2] && bb[2] == bb[3]) {
    int col = threadIdx.x;
    int b = bb[0];
#pragma unroll
    for (int v = 0; v < VV; ++v) {
      float sum = red[0][v][col] + red[1][v][col] + red[2][v][col] + red[3][v][col];
      atomicAdd(&part[(((size_t)v * SS + strip) * BB + b) * HH + col], sum);
    }
  } else {
    int b = bb[w];
#pragma unroll
    for (int v = 0; v < VV; ++v)
#pragma unroll
      for (int k = 0; k < 4; ++k)
        atomicAdd(&part[(((size_t)v * SS + strip) * BB + b) * HH + lane * 4 + k],
                  red[w][v][lane * 4 + k]);
  }
}

// ---------------- head: meanpool -> @W2+b2 -> @Wc+bc -> softmax ----------------
__global__ __launch_bounds__(256) void k_head(const float* __restrict__ part,
                                              const int* __restrict__ bptr,
                                              const float* __restrict__ W2,
                                              const float* __restrict__ b2,
                                              const float* __restrict__ Wc,
                                              const float* __restrict__ bc,
                                              float* __restrict__ probs,
                                              float* __restrict__ logits) {
  int v = blockIdx.x / BB;
  int b = blockIdx.x % BB;
  int h = threadIdx.x;
  __shared__ float mr[HH];
  __shared__ float vr[HH];
  __shared__ float scs[CC];
  float acc = 0.f;
  for (int s = 0; s < SS; ++s)
    acc += part[(((size_t)v * SS + s) * BB + b) * HH + h];
  int cnt = bptr[b + 1] - bptr[b]; if (cnt < 1) cnt = 1;
  mr[h] = acc / (float)cnt;
  __syncthreads();
  float a = b2[h];
  for (int k = 0; k < HH; ++k) a += mr[k] * W2[k * HH + h];
  vr[h] = a;
  __syncthreads();
  if (h < CC) {
    float t = bc[h];
    for (int k = 0; k < HH; ++k) t += vr[k] * Wc[k * CC + h];
    scs[h] = t;
  }
  __syncthreads();
  if (h < CC) {
    float m = scs[0];
    for (int c = 1; c < CC; ++c) m = fmaxf(m, scs[c]);
    float den = 0.f;
    for (int c = 0; c < CC; ++c) den += expf(scs[c] - m);
    float p = expf(scs[h] - m) / den;
    probs[((size_t)v * BB + b) * CC + h] = p;
    if (v == 0) logits[b * CC + h] = scs[h];
  }
}

// ---------------- loss: consistency + entropy ----------------
__global__ __launch_bounds__(256) void k_loss(const float* __restrict__ probs, float* __restrict__ out) {
  __shared__ float mp[BB * CC];
  __shared__ float red[8];
  int tid = threadIdx.x;
  float ent = 0.f;
  for (int i = tid; i < BB * CC; i += 256) {
    float m = 0.25f * (probs[i] + probs[BB * CC + i] + probs[2 * BB * CC + i] + probs[3 * BB * CC + i]);
    mp[i] = m;
    ent += m * logf(m + 1e-8f);
  }
  __syncthreads();
  float cons = 0.f;
  for (int i = tid; i < VV * BB * CC; i += 256) {
    float d = probs[i] - mp[i % (BB * CC)];
    cons += d * d;
  }
  for (int o = 32; o > 0; o >>= 1) {
    cons += __shfl_down(cons, o, 64);
    ent += __shfl_down(ent, o, 64);
  }
  int wid = tid >> 6, lane = tid & 63;
  if (lane == 0) { red[wid] = cons; red[4 + wid] = ent; }
  __syncthreads();
  if (tid == 0) {
    float c = red[0] + red[1] + red[2] + red[3];
    float e2 = red[4] + red[5] + red[6] + red[7];
    out[0] = c / (float)(VV * BB) - e2 / (float)BB;
  }
}

extern "C" void kernel_launch(void* const* d_in, const int* in_sizes, int n_in,
                              void* d_out, int out_size, void* d_ws, size_t ws_size,
                              hipStream_t stream) {
  const float* x     = (const float*)d_in[0];
  const int*   erow  = (const int*)d_in[1];
  const int*   ecol  = ((const int*)d_in[1]) + EE;
  const int*   batch = (const int*)d_in[2];
  const float* dm    = (const float*)d_in[3];
  const float* nmask = (const float*)d_in[4];
  const float* W1    = (const float*)d_in[5];
  const float* b1    = (const float*)d_in[6];
  const float* W2    = (const float*)d_in[7];
  const float* b2    = (const float*)d_in[8];
  const float* Wc    = (const float*)d_in[9];
  const float* bc    = (const float*)d_in[10];
  float* out = (float*)d_out;

  char* ws = (char*)d_ws;
  size_t off = 0;
  auto carve = [&](size_t bytes) -> char* {
    char* p = ws + off;
    off = (off + bytes + 255) & ~(size_t)255;
    return p;
  };
  float* part  = (float*)carve((size_t)VV * SS * BB * HH * 4);
  int*   deg   = (int*)carve((size_t)NN * 4);
  int*   fill  = (int*)carve((size_t)NN * 4);
  int*   rptr  = (int*)carve((size_t)(NN + 1) * 4);
  int*   csort = (int*)carve((size_t)EE * 4);
  int*   bptr  = (int*)carve((size_t)(BB + 1) * 4);
  int*   bsum  = (int*)carve(256 * 4);
  int*   boff  = (int*)carve(256 * 4);
  float* probs = (float*)carve((size_t)VV * BB * CC * 4);
  float4* m4   = (float4*)carve((size_t)NN * 16);
  _Float16* wf = (_Float16*)carve((size_t)8 * 16 * 64 * 8 * 2);

  const size_t NFh = (size_t)NN * FF * 2;
  __half* y  = (__half*)carve(NFh);                    // GEMM out fp16 (25.6 MB)
  uint4* h8a = (uint4*)carve((size_t)NN * 64 * 16);    // 51.2 MB interleaved 4-view fp8
  uint4* h8b = (uint4*)carve((size_t)NN * 64 * 16);    // 51.2 MB

  hipMemsetAsync(deg, 0, (size_t)NN * 4, stream);
  hipMemsetAsync(fill, 0, (size_t)NN * 4, stream);
  hipMemsetAsync(part, 0, (size_t)VV * SS * BB * HH * 4, stream);

  k_deg<<<(EE + 255) / 256, 256, 0, stream>>>(erow, deg);
  k_scan1<<<NBLK, 256, 0, stream>>>(deg, bsum);
  k_scan2<<<1, 256, 0, stream>>>(bsum, boff);
  k_scan3<<<NBLK, 256, 0, stream>>>(deg, boff, rptr);
  k_scatter<<<(EE + 255) / 256, 256, 0, stream>>>(erow, ecol, rptr, fill, csort);
  k_bptr<<<1, 256, 0, stream>>>(batch, bptr);
  k_packm<<<(NN + 255) / 256, 256, 0, stream>>>(nmask, m4);
  k_wfrag<<<32, 256, 0, stream>>>(W1, wf);

  k_gemm<<<(NN + 63) / 64, 256, 0, stream>>>(x, dm, wf, y);
  k_prop1<<<BPV, 256, 0, stream>>>(y, h8a, rptr, csort, m4);
  k_prop2a<<<BPV, 256, 0, stream>>>(h8a, h8b, rptr, csort);
  k_prop3a<<<BPV, 256, 0, stream>>>(h8b, rptr, csort, batch, b1, part);
  k_head<<<VV * BB, 256, 0, stream>>>(part, bptr, W2, b2, Wc, bc, probs, out);
  k_loss<<<1, 256, 0, stream>>>(probs, out + BB * CC);
}